// Round 16
// baseline (167.467 us; speedup 1.0000x reference)
//
#include <hip/hip_runtime.h>
#include <cfloat>
#include <cstdint>

// KNN classify via split-f16 MFMA emulated-fp32 GEMM.
// key = dot(x,t) - ||t||^2/2 ; dot = hiA*hiB + hiA*loB + loA*hiB (f32-accum MFMA).
// X_train pre-split into tile-packed f16 hi/lo; staged via global_load_lds.
// Top-5 largest keys, ties -> smaller train index (lax.top_k on -dist semantics).
// r16: r15 assembly + r10's validated dual accumulator chains (acc1=ks0-3+mh,
// acc2=ks4-7+ml, 1:1 interleave -> halves the 26-deep serial MFMA path that
// sets the per-tile critical path) under launch_bounds(256,3) (VGPR cap ~168;
// r10's regression was the (256,4) 64-VGPR cap spilling, not the arithmetic).

#define NTRAIN 100000
#define D 128
#define T 1024
#define TB 128          // tests per block (4 waves x 32)
#define NT 32           // trains per tile
#define KNN 5
#define NUM_CLASSES 10
#define NCH 125         // 125 chunks x 800 trains = 100000 exactly
#define CHUNK 800       // 25 tiles
#define NSUB 128        // threshold pre-pass sub-chunks
#define SCHUNK 64       // trains per pre-pass sub-chunk (2 tiles)
#define NTILE_TOT 3125  // NTRAIN / 32 exactly
#define TILE_HALVES 8192   // per packed tile: hi 4096 + lo 4096 halves (16KB)

typedef _Float16 half8 __attribute__((ext_vector_type(8)));
typedef float f32x16 __attribute__((ext_vector_type(16)));

#define MFMA(a, b, c) __builtin_amdgcn_mfma_f32_32x32x16_f16((a), (b), (c), 0, 0, 0)

struct Cand { float s; int j; };

__device__ __forceinline__ bool better(float s, int j, const Cand& c) {
    return (s > c.s) || (s == c.s && j < c.j);
}

__device__ __forceinline__ void ins5(Cand t5[KNN], float s, int j) {
    if (!better(s, j, t5[4])) return;
    if (better(s, j, t5[0]))      { t5[4]=t5[3]; t5[3]=t5[2]; t5[2]=t5[1]; t5[1]=t5[0]; t5[0]={s,j}; }
    else if (better(s, j, t5[1])) { t5[4]=t5[3]; t5[3]=t5[2]; t5[2]=t5[1]; t5[1]={s,j}; }
    else if (better(s, j, t5[2])) { t5[4]=t5[3]; t5[3]=t5[2]; t5[2]={s,j}; }
    else if (better(s, j, t5[3])) { t5[4]=t5[3]; t5[3]={s,j}; }
    else                          { t5[4]={s,j}; }
}

// score-only insert (5 largest values with multiplicity; exact for thresholds)
__device__ __forceinline__ void ins5f(float b[KNN], float s) {
    if (!(s > b[4])) return;
    if (s > b[0])      { b[4]=b[3]; b[3]=b[2]; b[2]=b[1]; b[1]=b[0]; b[0]=s; }
    else if (s > b[1]) { b[4]=b[3]; b[3]=b[2]; b[2]=b[1]; b[1]=s; }
    else if (s > b[2]) { b[4]=b[3]; b[3]=b[2]; b[2]=s; }
    else if (s > b[3]) { b[4]=b[3]; b[3]=s; }
    else               { b[4]=s; }
}

__device__ __forceinline__ void gload_lds16(const void* g, void* l) {
    __builtin_amdgcn_global_load_lds(
        (const __attribute__((address_space(1))) uint32_t*)g,
        (__attribute__((address_space(3))) uint32_t*)l, 16, 0, 0);
}

// ---- norms only (fallback path) — tree bit-matches r2..r15 validated kernels ----
__global__ __launch_bounds__(256)
void knn_norms(const float* __restrict__ XT, uint32_t* __restrict__ nrmp) {
    const int j = blockIdx.x * 256 + threadIdx.x;
    if (j >= NTRAIN) return;
    const float4* row = (const float4*)&XT[(size_t)j * D];
    float p[32];
#pragma unroll
    for (int c = 0; c < 32; ++c) {
        float4 v = row[c];
        p[c] = v.x * v.x + v.y * v.y + v.z * v.z + v.w * v.w;
    }
#pragma unroll
    for (int s = 1; s < 32; s <<= 1)
#pragma unroll
        for (int i = 0; i < 32; i += 2 * s) p[i] += p[i + s];
    const float m = -0.5f * p[0];
    const _Float16 mh = (_Float16)m;
    const _Float16 ml = (_Float16)(m - (float)mh);
    union { _Float16 h[2]; uint32_t u; } cv;
    cv.h[0] = mh; cv.h[1] = ml;
    nrmp[j] = cv.u;
}

// ---- pack XT into tile-packed hi/lo f16 + packed norms (r15-validated) ----
__global__ __launch_bounds__(256)
void knn_pack(const float* __restrict__ XT, _Float16* __restrict__ XTs,
              uint32_t* __restrict__ nrmp) {
    const int tid  = threadIdx.x;
    const int tile = blockIdx.x;
    const float* base = &XT[(size_t)tile * 32 * D];

    {   // pack: thread -> (ks, kh, row pair), 8 consecutive floats per row
        const int ks = tid >> 5, kh = (tid >> 4) & 1, rp = (tid & 15) * 2;
        const int c0 = ks * 16 + kh * 8;
        _Float16* outp = &XTs[(size_t)tile * TILE_HALVES + tid * 16];
#pragma unroll
        for (int rr = 0; rr < 2; ++rr) {
            const float* s = &base[(rp + rr) * D + c0];
            float4 v0 = *(const float4*)&s[0];
            float4 v1 = *(const float4*)&s[4];
            float a[8] = {v0.x, v0.y, v0.z, v0.w, v1.x, v1.y, v1.z, v1.w};
            half8 hv, lv;
#pragma unroll
            for (int e = 0; e < 8; ++e) {
                float v = a[e];
                _Float16 hh = (_Float16)v;
                hv[e] = hh; lv[e] = (_Float16)(v - (float)hh);
            }
            *(half8*)&outp[rr * 8]        = hv;
            *(half8*)&outp[4096 + rr * 8] = lv;
        }
    }
    {   // norms: thread -> (row, seg of 4 float4s); pairing tree as knn_norms
        const int row = tid >> 3, seg = tid & 7;
        const float4* rp4 = (const float4*)&base[row * D];
        float q[4];
#pragma unroll
        for (int c = 0; c < 4; ++c) {
            float4 v = rp4[seg * 4 + c];
            q[c] = v.x * v.x + v.y * v.y + v.z * v.z + v.w * v.w;
        }
        float part = (q[0] + q[1]) + (q[2] + q[3]);
        part += __shfl_xor(part, 1);
        part += __shfl_xor(part, 2);
        part += __shfl_xor(part, 4);
        if (seg == 0) {
            const float m = -0.5f * part;
            const _Float16 mh = (_Float16)m;
            const _Float16 ml = (_Float16)(m - (float)mh);
            union { _Float16 h[2]; uint32_t u; } cv;
            cv.h[0] = mh; cv.h[1] = ml;
            nrmp[tile * 32 + row] = cv.u;
        }
    }
}

// THRESH=true : pre-pass over sample sub-chunk bc (SCHUNK trains); writes the
//               exact per-test top-5 SCORES of that sub-chunk to thrc5.
// THRESH=false: main pass; top-5 seeded with thr[test] (exact 5th-best of the
//               merged 8192-train sample -> <= global 5th-best -> excludes nothing).
// 1D grid 8*ceil8(nch); XCD-aware decode puts all 8 bx of one bc on one XCD.
template <bool SPLIT, bool THRESH>
__global__ __launch_bounds__(256, 3)
void knn_mfma(const float* __restrict__ X, const float* __restrict__ XT,
              const _Float16* __restrict__ XTs, const uint32_t* __restrict__ nrmp,
              Cand* __restrict__ part, int nch, int chunk,
              const float* __restrict__ thrb, float* __restrict__ thrc5) {
    __shared__ __align__(16) _Float16 lds[2][TILE_HALVES];   // 32 KB

    const int tid  = threadIdx.x;
    const int lane = tid & 63;
    const int wv   = tid >> 6;

    // ---- XCD-aware decode ----
    const int L   = blockIdx.x;
    const int xcd = L & 7;
    const int s_  = L >> 3;
    const int bx  = s_ & 7;                 // test group of 128
    const int bc  = (s_ & ~7) | xcd;        // chunk
    if (bc >= nch) return;                  // uniform whole-block exit (pre-barrier)

    // ---- persistent B (tests) fragment: ONE colfrag per wave (32 tests) ----
    half8 Bh[8], Bl[8];
    {
        const int trow = bx * TB + wv * 32 + (lane & 31);
        const float* xp = &X[(size_t)trow * D + (lane >> 5) * 8];
#pragma unroll
        for (int ks = 0; ks < 8; ++ks) {
            float4 v0 = *(const float4*)&xp[ks * 16];
            float4 v1 = *(const float4*)&xp[ks * 16 + 4];
            float a[8] = {v0.x, v0.y, v0.z, v0.w, v1.x, v1.y, v1.z, v1.w};
#pragma unroll
            for (int e = 0; e < 8; ++e) {
                _Float16 hh = (_Float16)a[e];
                Bh[ks][e] = hh;
                Bl[ks][e] = (_Float16)(a[e] - (float)hh);
            }
        }
    }
    half8 B8;
#pragma unroll
    for (int e = 0; e < 8; ++e) B8[e] = (_Float16)0.0f;
    if (lane < 32) B8[0] = (_Float16)1.0f;

    // persistent zero accumulator source (C operand of chain-start MFMAs)
    f32x16 kZero;
#pragma unroll
    for (int e = 0; e < 16; ++e) kZero[e] = 0.f;

    const int srow = tid & 31;
    const int ksp  = tid >> 5;
    float a16[16];

    _Float16* const l0 = &lds[0][wv * 512];
    _Float16* const l1 = &lds[1][wv * 512];

    auto issue_stage_split = [&](int buf, const _Float16* g) {
        _Float16* l = buf ? l1 : l0;
#pragma unroll
        for (int p = 0; p < 4; ++p)
            gload_lds16(g + p * 2048, l + p * 2048);
    };
    auto issue_loads = [&](int jb) {
        int j = jb + srow;
        if (j > NTRAIN - 1) j = NTRAIN - 1;
        const float4* p = (const float4*)&XT[(size_t)j * D + ksp * 16];
        float4 v0 = p[0], v1 = p[1], v2 = p[2], v3 = p[3];
        a16[0]=v0.x; a16[1]=v0.y; a16[2]=v0.z; a16[3]=v0.w;
        a16[4]=v1.x; a16[5]=v1.y; a16[6]=v1.z; a16[7]=v1.w;
        a16[8]=v2.x; a16[9]=v2.y; a16[10]=v2.z; a16[11]=v2.w;
        a16[12]=v3.x; a16[13]=v3.y; a16[14]=v3.z; a16[15]=v3.w;
    };
    auto write_stage = [&](int buf) {
        half8 hv0, lv0, hv1, lv1;
#pragma unroll
        for (int e = 0; e < 8; ++e) {
            _Float16 hh = (_Float16)a16[e];
            hv0[e] = hh; lv0[e] = (_Float16)(a16[e] - (float)hh);
        }
#pragma unroll
        for (int e = 0; e < 8; ++e) {
            _Float16 hh = (_Float16)a16[8 + e];
            hv1[e] = hh; lv1[e] = (_Float16)(a16[8 + e] - (float)hh);
        }
        _Float16* base = &lds[buf][ksp * 512 + srow * 8];
        *(half8*)(base)              = hv0;
        *(half8*)(base + 256)        = hv1;
        *(half8*)(base + 4096)       = lv0;
        *(half8*)(base + 4096 + 256) = lv1;
    };

    // ---- seed top-5 (main pass: exact sample 5th-best lower bound) ----
    float s0 = -FLT_MAX;
    if (!THRESH && thrb != nullptr) {
        const int col = bx * TB + wv * 32 + (lane & 31);
        s0 = thrb[col];
    }
    Cand top5[KNN];
#pragma unroll
    for (int e = 0; e < KNN; ++e) top5[e] = {s0, 0x7fffffff};

    const int jc0 = bc * chunk;
    const int ntiles = chunk >> 5;
    const int tile0 = jc0 >> 5;

    const _Float16* gcur = &XTs[(size_t)tile0 * TILE_HALVES + wv * 512 + lane * 8];

    if (SPLIT) {
        issue_stage_split(0, gcur);
    } else {
        issue_loads(jc0);
        write_stage(0);
    }
    __syncthreads();

    for (int t = 0; t < ntiles; ++t) {
        const int jb = jc0 + t * NT;
        if (!SPLIT && jb >= NTRAIN) break;          // fallback only (uniform)
        const int buf = t & 1;
        const bool more = (t + 1 < ntiles);

        if (SPLIT) {
            gcur += TILE_HALVES;
            if (more) issue_stage_split(buf ^ 1, gcur);
        } else {
            if (more) issue_loads(jb + NT);
        }

        // augment source (lanes 0..31 carry rows)
        int nj = jb + (lane & 31);
        if (!SPLIT && nj > NTRAIN - 1) nj = NTRAIN - 1;
        uint32_t nv = nrmp[nj];
        if (lane >= 32) nv = 0;

        const _Float16* rbase = &lds[buf][lane * 8];
        __builtin_amdgcn_s_setprio(1);
        // ---- dual accumulator chains (r10-validated arithmetic):
        // acc1 = ks0..3 (+mh), acc2 = ks4..7 (+ml), interleaved 1:1 so each
        // chain's MFMA latency hides under the other's issue.
        f32x16 acc1, acc2;
        {
            half8 ah0 = *(const half8*)(rbase);
            half8 al0 = *(const half8*)(rbase + 4096);
            half8 ah4 = *(const half8*)(rbase + 4 * 512);
            half8 al4 = *(const half8*)(rbase + 4096 + 4 * 512);
            acc1 = MFMA(ah0, Bh[0], kZero);
            acc2 = MFMA(ah4, Bh[4], kZero);
            acc1 = MFMA(ah0, Bl[0], acc1);
            acc2 = MFMA(ah4, Bl[4], acc2);
            acc1 = MFMA(al0, Bh[0], acc1);
            acc2 = MFMA(al4, Bh[4], acc2);
        }
#pragma unroll
        for (int ks = 1; ks < 4; ++ks) {
            half8 ah0 = *(const half8*)(rbase + ks * 512);
            half8 al0 = *(const half8*)(rbase + 4096 + ks * 512);
            half8 ah4 = *(const half8*)(rbase + (ks + 4) * 512);
            half8 al4 = *(const half8*)(rbase + 4096 + (ks + 4) * 512);
            acc1 = MFMA(ah0, Bh[ks], acc1);
            acc2 = MFMA(ah4, Bh[ks + 4], acc2);
            acc1 = MFMA(ah0, Bl[ks], acc1);
            acc2 = MFMA(ah4, Bl[ks + 4], acc2);
            acc1 = MFMA(al0, Bh[ks], acc1);
            acc2 = MFMA(al4, Bh[ks + 4], acc2);
        }
        {   // augmented passes: +mh on chain1, +ml on chain2
            union { uint32_t u; _Float16 h[2]; } cv; cv.u = nv;
            half8 augh, augl;
#pragma unroll
            for (int e = 0; e < 8; ++e) { augh[e] = (_Float16)0.0f; augl[e] = (_Float16)0.0f; }
            augh[0] = cv.h[0];
            augl[0] = cv.h[1];
            acc1 = MFMA(augh, B8, acc1);
            acc2 = MFMA(augl, B8, acc2);
        }
        __builtin_amdgcn_s_setprio(0);

        f32x16 acc;
#pragma unroll
        for (int e = 0; e < 16; ++e) acc[e] = acc1[e] + acc2[e];

        if (!SPLIT && more) write_stage(buf ^ 1);

        // All waves done reading lds[buf] (MFMA consumed); barrier now so
        // divergent epilogues overlap the next tile's staging.
        __syncthreads();

        // ---- epilogue: flat per-reg guards ----
        // '>=' so candidates equal to the seeded threshold reach the exact
        // comparator (seed entries have j=INF and lose all ties); per-lane
        // real j stream is ascending so real ties resolve correctly.
        const int rb = 4 * (lane >> 5);
#pragma unroll
        for (int reg = 0; reg < 16; ++reg) {
            const float s = acc[reg];
            if (s >= top5[4].s) {
                const int j = jb + (reg & 3) + 8 * (reg >> 2) + rb;
                if (SPLIT || j < NTRAIN) ins5(top5, s, j);
            }
        }
    }

    // ---- merge lane pairs (l <-> l+32), write partials / sample top-5 scores ----
    {
        float os[KNN]; int oj[KNN];
#pragma unroll
        for (int e = 0; e < KNN; ++e) {
            os[e] = __shfl_xor(top5[e].s, 32);
            oj[e] = __shfl_xor(top5[e].j, 32);
        }
#pragma unroll
        for (int e = 0; e < KNN; ++e) ins5(top5, os[e], oj[e]);
        if (lane < 32) {
            const int test = bx * TB + wv * 32 + lane;
            if (THRESH) {
                float* pp = &thrc5[((size_t)test * NSUB + bc) * KNN];
#pragma unroll
                for (int e = 0; e < KNN; ++e) pp[e] = top5[e].s;
            } else {
                Cand* pp = &part[((size_t)test * nch + bc) * KNN];
#pragma unroll
                for (int e = 0; e < KNN; ++e) pp[e] = top5[e];
            }
        }
    }
}

// ---- merge sample top-5 scores -> thr[test] = exact 5th-best over sample ----
__global__ __launch_bounds__(256)
void knn_thrmerge(const float* __restrict__ thrc5, float* __restrict__ thr) {
    const int tid  = threadIdx.x;
    const int lane = tid & 63;
    const int test = blockIdx.x * 4 + (tid >> 6);
    if (test >= T) return;

    float b[KNN];
#pragma unroll
    for (int e = 0; e < KNN; ++e) b[e] = -FLT_MAX;

    for (int c = lane; c < NSUB; c += 64) {
        const float* pp = &thrc5[((size_t)test * NSUB + c) * KNN];
#pragma unroll
        for (int e = 0; e < KNN; ++e) ins5f(b, pp[e]);
    }
#pragma unroll
    for (int off = 32; off >= 1; off >>= 1) {
        float os[KNN];
#pragma unroll
        for (int e = 0; e < KNN; ++e) os[e] = __shfl_xor(b[e], off);
#pragma unroll
        for (int e = 0; e < KNN; ++e) ins5f(b, os[e]);
    }
    if (lane == 0) thr[test] = b[4];
}

// ---- parallel vote: one wave per test; lanes split chunks, butterfly merge ----
__global__ __launch_bounds__(256)
void knn_vote2(const Cand* __restrict__ part, const int* __restrict__ y,
               float* __restrict__ out, int nch) {
    const int tid  = threadIdx.x;
    const int lane = tid & 63;
    const int test = blockIdx.x * 4 + (tid >> 6);
    if (test >= T) return;

    Cand best[KNN];
#pragma unroll
    for (int e = 0; e < KNN; ++e) best[e] = {-FLT_MAX, 0x7fffffff};

    for (int c = lane; c < nch; c += 64) {
        const Cand* pp = &part[((size_t)test * nch + c) * KNN];
#pragma unroll
        for (int e = 0; e < KNN; ++e) {
            const Cand cc = pp[e];
            if ((unsigned)cc.j < (unsigned)NTRAIN) ins5(best, cc.s, cc.j);
        }
    }
#pragma unroll
    for (int off = 32; off >= 1; off >>= 1) {
        float os[KNN]; int oj[KNN];
#pragma unroll
        for (int e = 0; e < KNN; ++e) {
            os[e] = __shfl_xor(best[e].s, off);
            oj[e] = __shfl_xor(best[e].j, off);
        }
#pragma unroll
        for (int e = 0; e < KNN; ++e)
            if ((unsigned)oj[e] < (unsigned)NTRAIN) ins5(best, os[e], oj[e]);
    }
    if (lane == 0) {
        int lbl[KNN];
#pragma unroll
        for (int e = 0; e < KNN; ++e) lbl[e] = y[best[e].j];
        int bestc = 0, bestcnt = -1;
#pragma unroll
        for (int c = 0; c < NUM_CLASSES; ++c) {
            int cnt = 0;
#pragma unroll
            for (int e = 0; e < KNN; ++e) cnt += (lbl[e] == c) ? 1 : 0;
            if (cnt > bestcnt) { bestcnt = cnt; bestc = c; }
        }
        out[test] = (float)bestc;
    }
}

static inline int grid_for(int nch) {   // 8 bx * ceil8(nch) sub-ids
    return 8 * (((nch + 7) / 8) * 8);
}

extern "C" void kernel_launch(void* const* d_in, const int* in_sizes, int n_in,
                              void* d_out, int out_size, void* d_ws, size_t ws_size,
                              hipStream_t stream) {
    const float* X  = (const float*)d_in[0];
    const float* XT = (const float*)d_in[1];
    const int*   y  = (const int*)d_in[2];
    // d_in[3] = k (always 5; hardcoded)

    const size_t xts_bytes  = (size_t)NTILE_TOT * TILE_HALVES * 2;        // 51.2 MB
    const size_t nrm_bytes  = ((size_t)NTRAIN * 4 + 255) & ~(size_t)255;  // 400128
    const size_t thr_bytes  = ((size_t)T * 4 + 255) & ~(size_t)255;       // 4 KB
    const size_t per_chunk  = (size_t)T * KNN * sizeof(Cand);             // 40960 B
    const size_t part_bytes = (size_t)NCH * per_chunk;                    // 5.12 MB
    // thrc5 (T*NSUB*5*4 = 2.62 MB) aliases part: consumed by thrmerge before
    // the main pass writes part. Stream-ordered -> safe.

    const size_t need_full = xts_bytes + nrm_bytes + thr_bytes + part_bytes;
    const size_t need_noth = xts_bytes + nrm_bytes + part_bytes;

    if (ws_size >= need_full) {
        _Float16* XTs  = (_Float16*)d_ws;
        uint32_t* nrmp = (uint32_t*)((char*)d_ws + xts_bytes);
        float*    thr  = (float*)((char*)d_ws + xts_bytes + nrm_bytes);
        Cand*     part = (Cand*)((char*)d_ws + xts_bytes + nrm_bytes + thr_bytes);
        float*    thrc5 = (float*)part;   // alias
        knn_pack<<<NTILE_TOT, 256, 0, stream>>>(XT, XTs, nrmp);
        knn_mfma<true, true><<<grid_for(NSUB), 256, 0, stream>>>(
            X, XT, XTs, nrmp, nullptr, NSUB, SCHUNK, nullptr, thrc5);
        knn_thrmerge<<<T / 4, 256, 0, stream>>>(thrc5, thr);
        knn_mfma<true, false><<<grid_for(NCH), 256, 0, stream>>>(
            X, XT, XTs, nrmp, part, NCH, CHUNK, thr, nullptr);
        knn_vote2<<<T / 4, 256, 0, stream>>>(part, y, (float*)d_out, NCH);
    } else if (ws_size >= need_noth) {
        // no room for threshold buffers: unseeded main pass
        _Float16* XTs  = (_Float16*)d_ws;
        uint32_t* nrmp = (uint32_t*)((char*)d_ws + xts_bytes);
        Cand*     part = (Cand*)((char*)d_ws + xts_bytes + nrm_bytes);
        knn_pack<<<NTILE_TOT, 256, 0, stream>>>(XT, XTs, nrmp);
        knn_mfma<true, false><<<grid_for(NCH), 256, 0, stream>>>(
            X, XT, XTs, nrmp, part, NCH, CHUNK, nullptr, nullptr);
        knn_vote2<<<T / 4, 256, 0, stream>>>(part, y, (float*)d_out, NCH);
    } else {
        // legacy fallback: in-loop conversion, smallest ws footprint
        uint32_t* nrmp = (uint32_t*)d_ws;
        Cand*     part = (Cand*)((char*)d_ws + nrm_bytes);
        int fch = NCH;
        if (nrm_bytes + (size_t)fch * per_chunk > ws_size) {
            size_t avail = (ws_size > nrm_bytes) ? (ws_size - nrm_bytes) : 0;
            fch = (int)(avail / per_chunk);
            if (fch < 1) fch = 1;
        }
        const int chunk = (((NTRAIN + fch - 1) / fch) + (NT - 1)) & ~(NT - 1);
        knn_norms<<<(NTRAIN + 255) / 256, 256, 0, stream>>>(XT, nrmp);
        knn_mfma<false, false><<<grid_for(fch), 256, 0, stream>>>(
            X, XT, nullptr, nrmp, part, fch, chunk, nullptr, nullptr);
        knn_vote2<<<T / 4, 256, 0, stream>>>(part, y, (float*)d_out, fch);
    }
}

// Round 17
// 148.669 us; speedup vs baseline: 1.1264x; 1.1264x over previous
//
#include <hip/hip_runtime.h>
#include <cfloat>
#include <cstdint>

// KNN classify via split-f16 MFMA emulated-fp32 GEMM.
// key = dot(x,t) - ||t||^2/2 ; dot = hiA*hiB + hiA*loB + loA*hiB (f32-accum MFMA).
// X_train pre-split into tile-packed f16 hi/lo; staged via global_load_lds.
// Norm folded via 2 augment MFMAs (per-acc chain bit-identical to r3..r15).
// Top-5 largest keys, ties -> smaller train index (lax.top_k on -dist semantics).
// r17: REVERT to r15 verbatim (measured best: 148.9us total, main 84.9us).
// r16's dual-chain under (256,3) did not spill (VGPR 72) but residency fell
// 32->23% and main regressed to 99.6us. Seven structural attacks on the main
// pass (dual-chain x3, pair-tiles, grid 1280, bounds(256,5), reg-stream) all
// regressed vs this configuration -> empirical optimum for this structure.

#define NTRAIN 100000
#define D 128
#define T 1024
#define TB 128          // tests per block (4 waves x 32)
#define NT 32           // trains per tile
#define KNN 5
#define NUM_CLASSES 10
#define NCH 125         // 125 chunks x 800 trains = 100000 exactly
#define CHUNK 800       // 25 tiles
#define NSUB 128        // threshold pre-pass sub-chunks
#define SCHUNK 64       // trains per pre-pass sub-chunk (2 tiles)
#define NTILE_TOT 3125  // NTRAIN / 32 exactly
#define TILE_HALVES 8192   // per packed tile: hi 4096 + lo 4096 halves (16KB)

typedef _Float16 half8 __attribute__((ext_vector_type(8)));
typedef float f32x16 __attribute__((ext_vector_type(16)));

#define MFMA(a, b, c) __builtin_amdgcn_mfma_f32_32x32x16_f16((a), (b), (c), 0, 0, 0)

struct Cand { float s; int j; };

__device__ __forceinline__ bool better(float s, int j, const Cand& c) {
    return (s > c.s) || (s == c.s && j < c.j);
}

__device__ __forceinline__ void ins5(Cand t5[KNN], float s, int j) {
    if (!better(s, j, t5[4])) return;
    if (better(s, j, t5[0]))      { t5[4]=t5[3]; t5[3]=t5[2]; t5[2]=t5[1]; t5[1]=t5[0]; t5[0]={s,j}; }
    else if (better(s, j, t5[1])) { t5[4]=t5[3]; t5[3]=t5[2]; t5[2]=t5[1]; t5[1]={s,j}; }
    else if (better(s, j, t5[2])) { t5[4]=t5[3]; t5[3]=t5[2]; t5[2]={s,j}; }
    else if (better(s, j, t5[3])) { t5[4]=t5[3]; t5[3]={s,j}; }
    else                          { t5[4]={s,j}; }
}

// score-only insert (5 largest values with multiplicity; exact for thresholds)
__device__ __forceinline__ void ins5f(float b[KNN], float s) {
    if (!(s > b[4])) return;
    if (s > b[0])      { b[4]=b[3]; b[3]=b[2]; b[2]=b[1]; b[1]=b[0]; b[0]=s; }
    else if (s > b[1]) { b[4]=b[3]; b[3]=b[2]; b[2]=b[1]; b[1]=s; }
    else if (s > b[2]) { b[4]=b[3]; b[3]=b[2]; b[2]=s; }
    else if (s > b[3]) { b[4]=b[3]; b[3]=s; }
    else               { b[4]=s; }
}

__device__ __forceinline__ void gload_lds16(const void* g, void* l) {
    __builtin_amdgcn_global_load_lds(
        (const __attribute__((address_space(1))) uint32_t*)g,
        (__attribute__((address_space(3))) uint32_t*)l, 16, 0, 0);
}

// ---- norms only (fallback path) — tree bit-matches r2..r15 validated kernels ----
__global__ __launch_bounds__(256)
void knn_norms(const float* __restrict__ XT, uint32_t* __restrict__ nrmp) {
    const int j = blockIdx.x * 256 + threadIdx.x;
    if (j >= NTRAIN) return;
    const float4* row = (const float4*)&XT[(size_t)j * D];
    float p[32];
#pragma unroll
    for (int c = 0; c < 32; ++c) {
        float4 v = row[c];
        p[c] = v.x * v.x + v.y * v.y + v.z * v.z + v.w * v.w;
    }
#pragma unroll
    for (int s = 1; s < 32; s <<= 1)
#pragma unroll
        for (int i = 0; i < 32; i += 2 * s) p[i] += p[i + s];
    const float m = -0.5f * p[0];
    const _Float16 mh = (_Float16)m;
    const _Float16 ml = (_Float16)(m - (float)mh);
    union { _Float16 h[2]; uint32_t u; } cv;
    cv.h[0] = mh; cv.h[1] = ml;
    nrmp[j] = cv.u;
}

// ---- pack XT into tile-packed hi/lo f16 + packed norms ----
// Direct global reads (no LDS roundtrip, no barrier); conversions and norm
// pairing tree bit-identical to r9..r15 validated kernels.
__global__ __launch_bounds__(256)
void knn_pack(const float* __restrict__ XT, _Float16* __restrict__ XTs,
              uint32_t* __restrict__ nrmp) {
    const int tid  = threadIdx.x;
    const int tile = blockIdx.x;
    const float* base = &XT[(size_t)tile * 32 * D];

    {   // pack: thread -> (ks, kh, row pair), 8 consecutive floats per row
        const int ks = tid >> 5, kh = (tid >> 4) & 1, rp = (tid & 15) * 2;
        const int c0 = ks * 16 + kh * 8;
        _Float16* outp = &XTs[(size_t)tile * TILE_HALVES + tid * 16];
#pragma unroll
        for (int rr = 0; rr < 2; ++rr) {
            const float* s = &base[(rp + rr) * D + c0];
            float4 v0 = *(const float4*)&s[0];
            float4 v1 = *(const float4*)&s[4];
            float a[8] = {v0.x, v0.y, v0.z, v0.w, v1.x, v1.y, v1.z, v1.w};
            half8 hv, lv;
#pragma unroll
            for (int e = 0; e < 8; ++e) {
                float v = a[e];
                _Float16 hh = (_Float16)v;
                hv[e] = hh; lv[e] = (_Float16)(v - (float)hh);
            }
            *(half8*)&outp[rr * 8]        = hv;
            *(half8*)&outp[4096 + rr * 8] = lv;
        }
    }
    {   // norms: thread -> (row, seg of 4 float4s); pairing tree as knn_norms
        const int row = tid >> 3, seg = tid & 7;
        const float4* rp4 = (const float4*)&base[row * D];
        float q[4];
#pragma unroll
        for (int c = 0; c < 4; ++c) {
            float4 v = rp4[seg * 4 + c];
            q[c] = v.x * v.x + v.y * v.y + v.z * v.z + v.w * v.w;
        }
        float part = (q[0] + q[1]) + (q[2] + q[3]);
        part += __shfl_xor(part, 1);
        part += __shfl_xor(part, 2);
        part += __shfl_xor(part, 4);
        if (seg == 0) {
            const float m = -0.5f * part;
            const _Float16 mh = (_Float16)m;
            const _Float16 ml = (_Float16)(m - (float)mh);
            union { _Float16 h[2]; uint32_t u; } cv;
            cv.h[0] = mh; cv.h[1] = ml;
            nrmp[tile * 32 + row] = cv.u;
        }
    }
}

// THRESH=true : pre-pass over sample sub-chunk bc (SCHUNK trains); writes the
//               exact per-test top-5 SCORES of that sub-chunk to thrc5.
// THRESH=false: main pass; top-5 seeded with thr[test] (exact 5th-best of the
//               merged 8192-train sample -> <= global 5th-best -> excludes nothing).
// 1D grid 8*ceil8(nch); XCD-aware decode puts all 8 bx of one bc on one XCD.
template <bool SPLIT, bool THRESH>
__global__ __launch_bounds__(256, 4)
void knn_mfma(const float* __restrict__ X, const float* __restrict__ XT,
              const _Float16* __restrict__ XTs, const uint32_t* __restrict__ nrmp,
              Cand* __restrict__ part, int nch, int chunk,
              const float* __restrict__ thrb, float* __restrict__ thrc5) {
    __shared__ __align__(16) _Float16 lds[2][TILE_HALVES];   // 32 KB

    const int tid  = threadIdx.x;
    const int lane = tid & 63;
    const int wv   = tid >> 6;

    // ---- XCD-aware decode ----
    const int L   = blockIdx.x;
    const int xcd = L & 7;
    const int s_  = L >> 3;
    const int bx  = s_ & 7;                 // test group of 128
    const int bc  = (s_ & ~7) | xcd;        // chunk
    if (bc >= nch) return;                  // uniform whole-block exit (pre-barrier)

    // ---- persistent B (tests) fragment: ONE colfrag per wave (32 tests) ----
    half8 Bh[8], Bl[8];
    {
        const int trow = bx * TB + wv * 32 + (lane & 31);
        const float* xp = &X[(size_t)trow * D + (lane >> 5) * 8];
#pragma unroll
        for (int ks = 0; ks < 8; ++ks) {
            float4 v0 = *(const float4*)&xp[ks * 16];
            float4 v1 = *(const float4*)&xp[ks * 16 + 4];
            float a[8] = {v0.x, v0.y, v0.z, v0.w, v1.x, v1.y, v1.z, v1.w};
#pragma unroll
            for (int e = 0; e < 8; ++e) {
                _Float16 hh = (_Float16)a[e];
                Bh[ks][e] = hh;
                Bl[ks][e] = (_Float16)(a[e] - (float)hh);
            }
        }
    }
    half8 B8;
#pragma unroll
    for (int e = 0; e < 8; ++e) B8[e] = (_Float16)0.0f;
    if (lane < 32) B8[0] = (_Float16)1.0f;

    // persistent zero accumulator source (C operand of chain-start MFMA)
    f32x16 kZero;
#pragma unroll
    for (int e = 0; e < 16; ++e) kZero[e] = 0.f;

    const int srow = tid & 31;
    const int ksp  = tid >> 5;
    float a16[16];

    _Float16* const l0 = &lds[0][wv * 512];
    _Float16* const l1 = &lds[1][wv * 512];

    auto issue_stage_split = [&](int buf, const _Float16* g) {
        _Float16* l = buf ? l1 : l0;
#pragma unroll
        for (int p = 0; p < 4; ++p)
            gload_lds16(g + p * 2048, l + p * 2048);
    };
    auto issue_loads = [&](int jb) {
        int j = jb + srow;
        if (j > NTRAIN - 1) j = NTRAIN - 1;
        const float4* p = (const float4*)&XT[(size_t)j * D + ksp * 16];
        float4 v0 = p[0], v1 = p[1], v2 = p[2], v3 = p[3];
        a16[0]=v0.x; a16[1]=v0.y; a16[2]=v0.z; a16[3]=v0.w;
        a16[4]=v1.x; a16[5]=v1.y; a16[6]=v1.z; a16[7]=v1.w;
        a16[8]=v2.x; a16[9]=v2.y; a16[10]=v2.z; a16[11]=v2.w;
        a16[12]=v3.x; a16[13]=v3.y; a16[14]=v3.z; a16[15]=v3.w;
    };
    auto write_stage = [&](int buf) {
        half8 hv0, lv0, hv1, lv1;
#pragma unroll
        for (int e = 0; e < 8; ++e) {
            _Float16 hh = (_Float16)a16[e];
            hv0[e] = hh; lv0[e] = (_Float16)(a16[e] - (float)hh);
        }
#pragma unroll
        for (int e = 0; e < 8; ++e) {
            _Float16 hh = (_Float16)a16[8 + e];
            hv1[e] = hh; lv1[e] = (_Float16)(a16[8 + e] - (float)hh);
        }
        _Float16* base = &lds[buf][ksp * 512 + srow * 8];
        *(half8*)(base)              = hv0;
        *(half8*)(base + 256)        = hv1;
        *(half8*)(base + 4096)       = lv0;
        *(half8*)(base + 4096 + 256) = lv1;
    };

    // ---- seed top-5 (main pass: exact sample 5th-best lower bound) ----
    float s0 = -FLT_MAX;
    if (!THRESH && thrb != nullptr) {
        const int col = bx * TB + wv * 32 + (lane & 31);
        s0 = thrb[col];
    }
    Cand top5[KNN];
#pragma unroll
    for (int e = 0; e < KNN; ++e) top5[e] = {s0, 0x7fffffff};

    const int jc0 = bc * chunk;
    const int ntiles = chunk >> 5;
    const int tile0 = jc0 >> 5;

    const _Float16* gcur = &XTs[(size_t)tile0 * TILE_HALVES + wv * 512 + lane * 8];

    if (SPLIT) {
        issue_stage_split(0, gcur);
    } else {
        issue_loads(jc0);
        write_stage(0);
    }
    __syncthreads();

    for (int t = 0; t < ntiles; ++t) {
        const int jb = jc0 + t * NT;
        if (!SPLIT && jb >= NTRAIN) break;          // fallback only (uniform)
        const int buf = t & 1;
        const bool more = (t + 1 < ntiles);

        if (SPLIT) {
            gcur += TILE_HALVES;
            if (more) issue_stage_split(buf ^ 1, gcur);
        } else {
            if (more) issue_loads(jb + NT);
        }

        // augment source (lanes 0..31 carry rows)
        int nj = jb + (lane & 31);
        if (!SPLIT && nj > NTRAIN - 1) nj = NTRAIN - 1;
        uint32_t nv = nrmp[nj];
        if (lane >= 32) nv = 0;

        const _Float16* rbase = &lds[buf][lane * 8];
        __builtin_amdgcn_s_setprio(1);
        f32x16 acc;
        {   // ks = 0: acc born from kZero (C operand), chain order as r3..r15
            half8 ah = *(const half8*)(rbase);
            half8 al = *(const half8*)(rbase + 4096);
            acc = MFMA(ah, Bh[0], kZero);
            acc = MFMA(ah, Bl[0], acc);
            acc = MFMA(al, Bh[0], acc);
        }
#pragma unroll
        for (int ks = 1; ks < 8; ++ks) {
            half8 ah = *(const half8*)(rbase + ks * 512);
            half8 al = *(const half8*)(rbase + 4096 + ks * 512);
            acc = MFMA(ah, Bh[ks], acc);
            acc = MFMA(ah, Bl[ks], acc);
            acc = MFMA(al, Bh[ks], acc);
        }
        {   // augmented passes (+mh then +ml) — same chain as validated rounds
            union { uint32_t u; _Float16 h[2]; } cv; cv.u = nv;
            half8 augh, augl;
#pragma unroll
            for (int e = 0; e < 8; ++e) { augh[e] = (_Float16)0.0f; augl[e] = (_Float16)0.0f; }
            augh[0] = cv.h[0];
            augl[0] = cv.h[1];
            acc = MFMA(augh, B8, acc);
            acc = MFMA(augl, B8, acc);
        }
        __builtin_amdgcn_s_setprio(0);

        if (!SPLIT && more) write_stage(buf ^ 1);

        // All waves done reading lds[buf] (MFMA consumed); barrier now so
        // divergent epilogues overlap the next tile's staging.
        __syncthreads();

        // ---- epilogue: flat per-reg guards ----
        // '>=' so candidates equal to the seeded threshold reach the exact
        // comparator (seed entries have j=INF and lose all ties); per-lane
        // real j stream is ascending so real ties resolve correctly.
        const int rb = 4 * (lane >> 5);
#pragma unroll
        for (int reg = 0; reg < 16; ++reg) {
            const float s = acc[reg];
            if (s >= top5[4].s) {
                const int j = jb + (reg & 3) + 8 * (reg >> 2) + rb;
                if (SPLIT || j < NTRAIN) ins5(top5, s, j);
            }
        }
    }

    // ---- merge lane pairs (l <-> l+32), write partials / sample top-5 scores ----
    {
        float os[KNN]; int oj[KNN];
#pragma unroll
        for (int e = 0; e < KNN; ++e) {
            os[e] = __shfl_xor(top5[e].s, 32);
            oj[e] = __shfl_xor(top5[e].j, 32);
        }
#pragma unroll
        for (int e = 0; e < KNN; ++e) ins5(top5, os[e], oj[e]);
        if (lane < 32) {
            const int test = bx * TB + wv * 32 + lane;
            if (THRESH) {
                float* pp = &thrc5[((size_t)test * NSUB + bc) * KNN];
#pragma unroll
                for (int e = 0; e < KNN; ++e) pp[e] = top5[e].s;
            } else {
                Cand* pp = &part[((size_t)test * nch + bc) * KNN];
#pragma unroll
                for (int e = 0; e < KNN; ++e) pp[e] = top5[e];
            }
        }
    }
}

// ---- merge sample top-5 scores -> thr[test] = exact 5th-best over sample ----
__global__ __launch_bounds__(256)
void knn_thrmerge(const float* __restrict__ thrc5, float* __restrict__ thr) {
    const int tid  = threadIdx.x;
    const int lane = tid & 63;
    const int test = blockIdx.x * 4 + (tid >> 6);
    if (test >= T) return;

    float b[KNN];
#pragma unroll
    for (int e = 0; e < KNN; ++e) b[e] = -FLT_MAX;

    for (int c = lane; c < NSUB; c += 64) {
        const float* pp = &thrc5[((size_t)test * NSUB + c) * KNN];
#pragma unroll
        for (int e = 0; e < KNN; ++e) ins5f(b, pp[e]);
    }
#pragma unroll
    for (int off = 32; off >= 1; off >>= 1) {
        float os[KNN];
#pragma unroll
        for (int e = 0; e < KNN; ++e) os[e] = __shfl_xor(b[e], off);
#pragma unroll
        for (int e = 0; e < KNN; ++e) ins5f(b, os[e]);
    }
    if (lane == 0) thr[test] = b[4];
}

// ---- parallel vote: one wave per test; lanes split chunks, butterfly merge ----
__global__ __launch_bounds__(256)
void knn_vote2(const Cand* __restrict__ part, const int* __restrict__ y,
               float* __restrict__ out, int nch) {
    const int tid  = threadIdx.x;
    const int lane = tid & 63;
    const int test = blockIdx.x * 4 + (tid >> 6);
    if (test >= T) return;

    Cand best[KNN];
#pragma unroll
    for (int e = 0; e < KNN; ++e) best[e] = {-FLT_MAX, 0x7fffffff};

    for (int c = lane; c < nch; c += 64) {
        const Cand* pp = &part[((size_t)test * nch + c) * KNN];
#pragma unroll
        for (int e = 0; e < KNN; ++e) {
            const Cand cc = pp[e];
            if ((unsigned)cc.j < (unsigned)NTRAIN) ins5(best, cc.s, cc.j);
        }
    }
#pragma unroll
    for (int off = 32; off >= 1; off >>= 1) {
        float os[KNN]; int oj[KNN];
#pragma unroll
        for (int e = 0; e < KNN; ++e) {
            os[e] = __shfl_xor(best[e].s, off);
            oj[e] = __shfl_xor(best[e].j, off);
        }
#pragma unroll
        for (int e = 0; e < KNN; ++e)
            if ((unsigned)oj[e] < (unsigned)NTRAIN) ins5(best, os[e], oj[e]);
    }
    if (lane == 0) {
        int lbl[KNN];
#pragma unroll
        for (int e = 0; e < KNN; ++e) lbl[e] = y[best[e].j];
        int bestc = 0, bestcnt = -1;
#pragma unroll
        for (int c = 0; c < NUM_CLASSES; ++c) {
            int cnt = 0;
#pragma unroll
            for (int e = 0; e < KNN; ++e) cnt += (lbl[e] == c) ? 1 : 0;
            if (cnt > bestcnt) { bestcnt = cnt; bestc = c; }
        }
        out[test] = (float)bestc;
    }
}

static inline int grid_for(int nch) {   // 8 bx * ceil8(nch) sub-ids
    return 8 * (((nch + 7) / 8) * 8);
}

extern "C" void kernel_launch(void* const* d_in, const int* in_sizes, int n_in,
                              void* d_out, int out_size, void* d_ws, size_t ws_size,
                              hipStream_t stream) {
    const float* X  = (const float*)d_in[0];
    const float* XT = (const float*)d_in[1];
    const int*   y  = (const int*)d_in[2];
    // d_in[3] = k (always 5; hardcoded)

    const size_t xts_bytes  = (size_t)NTILE_TOT * TILE_HALVES * 2;        // 51.2 MB
    const size_t nrm_bytes  = ((size_t)NTRAIN * 4 + 255) & ~(size_t)255;  // 400128
    const size_t thr_bytes  = ((size_t)T * 4 + 255) & ~(size_t)255;       // 4 KB
    const size_t per_chunk  = (size_t)T * KNN * sizeof(Cand);             // 40960 B
    const size_t part_bytes = (size_t)NCH * per_chunk;                    // 5.12 MB
    // thrc5 (T*NSUB*5*4 = 2.62 MB) aliases part: consumed by thrmerge before
    // the main pass writes part. Stream-ordered -> safe.

    const size_t need_full = xts_bytes + nrm_bytes + thr_bytes + part_bytes;
    const size_t need_noth = xts_bytes + nrm_bytes + part_bytes;

    if (ws_size >= need_full) {
        _Float16* XTs  = (_Float16*)d_ws;
        uint32_t* nrmp = (uint32_t*)((char*)d_ws + xts_bytes);
        float*    thr  = (float*)((char*)d_ws + xts_bytes + nrm_bytes);
        Cand*     part = (Cand*)((char*)d_ws + xts_bytes + nrm_bytes + thr_bytes);
        float*    thrc5 = (float*)part;   // alias
        knn_pack<<<NTILE_TOT, 256, 0, stream>>>(XT, XTs, nrmp);
        knn_mfma<true, true><<<grid_for(NSUB), 256, 0, stream>>>(
            X, XT, XTs, nrmp, nullptr, NSUB, SCHUNK, nullptr, thrc5);
        knn_thrmerge<<<T / 4, 256, 0, stream>>>(thrc5, thr);
        knn_mfma<true, false><<<grid_for(NCH), 256, 0, stream>>>(
            X, XT, XTs, nrmp, part, NCH, CHUNK, thr, nullptr);
        knn_vote2<<<T / 4, 256, 0, stream>>>(part, y, (float*)d_out, NCH);
    } else if (ws_size >= need_noth) {
        // no room for threshold buffers: unseeded main pass
        _Float16* XTs  = (_Float16*)d_ws;
        uint32_t* nrmp = (uint32_t*)((char*)d_ws + xts_bytes);
        Cand*     part = (Cand*)((char*)d_ws + xts_bytes + nrm_bytes);
        knn_pack<<<NTILE_TOT, 256, 0, stream>>>(XT, XTs, nrmp);
        knn_mfma<true, false><<<grid_for(NCH), 256, 0, stream>>>(
            X, XT, XTs, nrmp, part, NCH, CHUNK, nullptr, nullptr);
        knn_vote2<<<T / 4, 256, 0, stream>>>(part, y, (float*)d_out, NCH);
    } else {
        // legacy fallback: in-loop conversion, smallest ws footprint
        uint32_t* nrmp = (uint32_t*)d_ws;
        Cand*     part = (Cand*)((char*)d_ws + nrm_bytes);
        int fch = NCH;
        if (nrm_bytes + (size_t)fch * per_chunk > ws_size) {
            size_t avail = (ws_size > nrm_bytes) ? (ws_size - nrm_bytes) : 0;
            fch = (int)(avail / per_chunk);
            if (fch < 1) fch = 1;
        }
        const int chunk = (((NTRAIN + fch - 1) / fch) + (NT - 1)) & ~(NT - 1);
        knn_norms<<<(NTRAIN + 255) / 256, 256, 0, stream>>>(XT, nrmp);
        knn_mfma<false, false><<<grid_for(fch), 256, 0, stream>>>(
            X, XT, nullptr, nrmp, part, fch, chunk, nullptr, nullptr);
        knn_vote2<<<T / 4, 256, 0, stream>>>(part, y, (float*)d_out, fch);
    }
}